// Round 1
// baseline (633.285 us; speedup 1.0000x reference)
//
#include <hip/hip_runtime.h>
#include <hip/hip_bf16.h>

#define B_    16
#define N_    4
#define COUT  256
#define CIN   256
#define H_    64
#define W_    64
#define K_TOT (CIN * 9)   // 2304
#define HW    (H_ * W_)   // 4096

typedef __attribute__((ext_vector_type(8))) short short8;
typedef __attribute__((ext_vector_type(4))) float f32x4;

static __device__ __forceinline__ unsigned short f2bf(float f) {
    __hip_bfloat16 h = __float2bfloat16(f);
    return *reinterpret_cast<unsigned short*>(&h);
}

// ---------------------------------------------------------------------------
// Kernel 1: 9x9 rotation matrices, scaled by alpha.  rm[b*N_+n][9][9] floats.
// ---------------------------------------------------------------------------
__global__ void rot_mats_kernel(const float* __restrict__ alphas,
                                const float* __restrict__ angles,
                                float* __restrict__ rm) {
    int i = threadIdx.x;
    if (i >= B_ * N_) return;
    float th = angles[i], al = alphas[i];
    float xc = cosf(th), ys = sinf(th);
    float a = xc - ys, b = xc * ys, c = xc + ys;
    float r[81];
#pragma unroll
    for (int j = 0; j < 81; ++j) r[j] = 0.f;
    if (th >= 0.f) {
        r[0] = a;          r[1] = 1.f - a;
        r[10] = xc - b;    r[11] = b;        r[13] = 1.f - c + b; r[14] = ys - b;
        r[20] = a;         r[23] = 1.f - a;
        r[27] = b;         r[28] = ys - b;   r[30] = xc - b;      r[31] = 1.f - c + b;
        r[40] = 1.f;
        r[49] = 1.f - c + b; r[50] = xc - b; r[52] = ys - b;      r[53] = b;
        r[57] = 1.f - a;   r[60] = a;
        r[66] = ys - b;    r[67] = 1.f - c + b; r[69] = b;        r[70] = xc - b;
        r[79] = 1.f - a;   r[80] = a;
    } else {
        r[0] = c;          r[3] = 1.f - c;
        r[9] = -b;         r[10] = xc + b;   r[12] = b - ys;      r[13] = 1.f - a - b;
        r[19] = 1.f - c;   r[20] = c;
        r[30] = xc + b;    r[31] = 1.f - a - b; r[33] = -b;       r[34] = b - ys;
        r[40] = 1.f;
        r[46] = b - ys;    r[47] = -b;       r[49] = 1.f - a - b; r[50] = xc + b;
        r[60] = c;         r[61] = 1.f - c;
        r[67] = 1.f - a - b; r[68] = b - ys; r[70] = xc + b;      r[71] = -b;
        r[77] = 1.f - c;   r[80] = c;
    }
#pragma unroll
    for (int j = 0; j < 81; ++j) rm[i * 81 + j] = r[j] * al;
}

// ---------------------------------------------------------------------------
// Kernel 2: rw[b][cout][cin*9 + p] (bf16) = sum_n sum_q rm[b][n][p][q] *
//           weight[n][cout][cin][q]
// ---------------------------------------------------------------------------
__global__ __launch_bounds__(256)
void build_rw_kernel(const float* __restrict__ weight,
                     const float* __restrict__ rm,
                     unsigned short* __restrict__ rw) {
    __shared__ float rms[B_ * N_ * 81];   // 5184 floats = 20.7 KB
    int tid = threadIdx.x;
    for (int j = tid; j < B_ * N_ * 81; j += 256) rms[j] = rm[j];
    __syncthreads();

    int idx = blockIdx.x * 256 + tid;     // cout*256 + cin
    int cout = idx >> 8, cin = idx & 255;

    float wv[N_][9];
#pragma unroll
    for (int n = 0; n < N_; ++n)
#pragma unroll
        for (int q = 0; q < 9; ++q)
            wv[n][q] = weight[(size_t)(n * (COUT * CIN) + idx) * 9 + q];

    for (int b = 0; b < B_; ++b) {
        const float* rmb = &rms[b * N_ * 81];
        unsigned short* dst = rw + (size_t)(b * COUT + cout) * K_TOT + cin * 9;
#pragma unroll
        for (int p = 0; p < 9; ++p) {
            float s = 0.f;
#pragma unroll
            for (int n = 0; n < N_; ++n)
#pragma unroll
                for (int q = 0; q < 9; ++q)
                    s += rmb[n * 81 + p * 9 + q] * wv[n][q];
            dst[p] = f2bf(s);
        }
    }
}

// ---------------------------------------------------------------------------
// Kernel 3: implicit-GEMM conv. Per sample b: D[cout][pixel] =
//           sum_k A[cout][k] * B[k][pixel], k = cin*9 + (ph*3+pw).
// Block: 256 thr (4 waves 2x2). Tile: 64 couts x 64 pixels (one image row y).
// ---------------------------------------------------------------------------
__global__ __launch_bounds__(256)
void conv_kernel(const float* __restrict__ x,
                 const unsigned short* __restrict__ rw,
                 float* __restrict__ out) {
    int bid = blockIdx.x;
    int mt = bid & 3;           // cout tile (4)
    int y  = (bid >> 2) & 63;   // image row
    int b  = bid >> 8;          // sample
    int m0 = mt * 64;
    int tid = threadIdx.x;

    __shared__ __align__(16) unsigned short As[64][40];  // 64 couts x 32 k (+pad)
    __shared__ __align__(16) unsigned short Bs[64][40];  // 64 pixels x 32 k (+pad)

    int lane = tid & 63;
    int wid  = tid >> 6;
    int wr = wid >> 1, wc = wid & 1;

    f32x4 acc[2][2] = {};

    const unsigned short* rwb = rw + (size_t)(b * COUT + m0) * K_TOT;
    const float* xb = x + (size_t)b * CIN * HW;

    int arow = tid >> 2, aseg = tid & 3;   // A staging: 64 rows x 4 x 16B
    int px = tid & 63;                     // B gather pixel

    for (int kt = 0; kt < K_TOT / 32; ++kt) {
        int k0 = kt * 32;
        // ---- stage A tile (rw is contiguous in k) ----
        {
            const int4 v = *(const int4*)(rwb + (size_t)arow * K_TOT + k0 + aseg * 8);
            *(int4*)(&As[arow][aseg * 8]) = v;
        }
        // ---- stage B tile: im2col gather, coalesced 64-wide row reads ----
#pragma unroll
        for (int it = 0; it < 8; ++it) {
            int kk = it * 4 + wid;                 // 0..31
            unsigned int k = (unsigned int)(k0 + kk);
            unsigned int cin = k / 9u;
            unsigned int p3 = k - cin * 9u;
            int ph = (int)(p3 / 3u), pw = (int)(p3 - (p3 / 3u) * 3u);
            int yy = y + ph - 1, xx = px + pw - 1;
            float v = 0.f;
            if (yy >= 0 && yy < H_ && xx >= 0 && xx < W_)
                v = xb[((size_t)cin * H_ + yy) * W_ + xx];
            Bs[px][kk] = f2bf(v);
        }
        __syncthreads();

        // ---- fragments + MFMA ----
        int kb = (lane >> 4) * 8;
        int rA = lane & 15;
        short8 af0 = *(const short8*)(&As[wr * 32 + rA][kb]);
        short8 af1 = *(const short8*)(&As[wr * 32 + 16 + rA][kb]);
        short8 bf0 = *(const short8*)(&Bs[wc * 32 + rA][kb]);
        short8 bf1 = *(const short8*)(&Bs[wc * 32 + 16 + rA][kb]);
        acc[0][0] = __builtin_amdgcn_mfma_f32_16x16x32_bf16(af0, bf0, acc[0][0], 0, 0, 0);
        acc[0][1] = __builtin_amdgcn_mfma_f32_16x16x32_bf16(af0, bf1, acc[0][1], 0, 0, 0);
        acc[1][0] = __builtin_amdgcn_mfma_f32_16x16x32_bf16(af1, bf0, acc[1][0], 0, 0, 0);
        acc[1][1] = __builtin_amdgcn_mfma_f32_16x16x32_bf16(af1, bf1, acc[1][1], 0, 0, 0);
        __syncthreads();
    }

    // ---- epilogue: D[row=(lane>>4)*4+r][col=lane&15] ----
    int row0 = (lane >> 4) * 4;
    int col  = lane & 15;
    float* outb = out + (size_t)(b * COUT + m0) * HW + y * W_;
#pragma unroll
    for (int mi = 0; mi < 2; ++mi)
#pragma unroll
        for (int ni = 0; ni < 2; ++ni)
#pragma unroll
            for (int r = 0; r < 4; ++r) {
                int m = wr * 32 + mi * 16 + row0 + r;
                int n = wc * 32 + ni * 16 + col;
                outb[(size_t)m * HW + n] = acc[mi][ni][r];
            }
}

// ---------------------------------------------------------------------------
extern "C" void kernel_launch(void* const* d_in, const int* in_sizes, int n_in,
                              void* d_out, int out_size, void* d_ws, size_t ws_size,
                              hipStream_t stream) {
    const float* x      = (const float*)d_in[0];
    const float* alphas = (const float*)d_in[1];
    const float* angles = (const float*)d_in[2];
    const float* weight = (const float*)d_in[3];
    float* out = (float*)d_out;

    unsigned short* rw = (unsigned short*)d_ws;                       // 18.9 MB bf16
    float* rm = (float*)((char*)d_ws + (size_t)B_ * COUT * K_TOT * 2); // 20.7 KB

    rot_mats_kernel<<<1, 64, 0, stream>>>(alphas, angles, rm);
    build_rw_kernel<<<COUT * CIN / 256, 256, 0, stream>>>(weight, rm, rw);
    conv_kernel<<<B_ * H_ * (COUT / 64), 256, 0, stream>>>(x, rw, out);
}

// Round 3
// 162.984 us; speedup vs baseline: 3.8856x; 3.8856x over previous
//
#include <hip/hip_runtime.h>
#include <hip/hip_bf16.h>

#define B_    16
#define N_    4
#define COUT  256
#define CIN   256
#define H_    64
#define W_    64
#define K_TOT (CIN * 9)   // 2304, k = p*256 + cin  (p-major)
#define HW    (H_ * W_)   // 4096

typedef __attribute__((ext_vector_type(8))) short short8;
typedef __attribute__((ext_vector_type(4))) float f32x4;
typedef unsigned short ushort_t;

static __device__ __forceinline__ ushort_t f2bf(float f) {
    __hip_bfloat16 h = __float2bfloat16(f);
    return *reinterpret_cast<ushort_t*>(&h);
}

// ---------------------------------------------------------------------------
// Kernel 1: 9x9 rotation matrices, scaled by alpha.  rm[b*N_+n][9][9] floats.
// ---------------------------------------------------------------------------
__global__ void rot_mats_kernel(const float* __restrict__ alphas,
                                const float* __restrict__ angles,
                                float* __restrict__ rm) {
    int i = threadIdx.x;
    if (i >= B_ * N_) return;
    float th = angles[i], al = alphas[i];
    float xc = cosf(th), ys = sinf(th);
    float a = xc - ys, b = xc * ys, c = xc + ys;
    float r[81];
#pragma unroll
    for (int j = 0; j < 81; ++j) r[j] = 0.f;
    if (th >= 0.f) {
        r[0] = a;          r[1] = 1.f - a;
        r[10] = xc - b;    r[11] = b;        r[13] = 1.f - c + b; r[14] = ys - b;
        r[20] = a;         r[23] = 1.f - a;
        r[27] = b;         r[28] = ys - b;   r[30] = xc - b;      r[31] = 1.f - c + b;
        r[40] = 1.f;
        r[49] = 1.f - c + b; r[50] = xc - b; r[52] = ys - b;      r[53] = b;
        r[57] = 1.f - a;   r[60] = a;
        r[66] = ys - b;    r[67] = 1.f - c + b; r[69] = b;        r[70] = xc - b;
        r[79] = 1.f - a;   r[80] = a;
    } else {
        r[0] = c;          r[3] = 1.f - c;
        r[9] = -b;         r[10] = xc + b;   r[12] = b - ys;      r[13] = 1.f - a - b;
        r[19] = 1.f - c;   r[20] = c;
        r[30] = xc + b;    r[31] = 1.f - a - b; r[33] = -b;       r[34] = b - ys;
        r[40] = 1.f;
        r[46] = b - ys;    r[47] = -b;       r[49] = 1.f - a - b; r[50] = xc + b;
        r[60] = c;         r[61] = 1.f - c;
        r[67] = 1.f - a - b; r[68] = b - ys; r[70] = xc + b;      r[71] = -b;
        r[77] = 1.f - c;   r[80] = c;
    }
#pragma unroll
    for (int j = 0; j < 81; ++j) rm[i * 81 + j] = r[j] * al;
}

// ---------------------------------------------------------------------------
// Kernel 2: rw[b][cout][p*256 + cin] (bf16, p-major K layout)
//   = sum_n sum_q rm[b][n][p][q] * weight[n][cout][cin][q]
// grid: (COUT*CIN/256, B_)
// ---------------------------------------------------------------------------
__global__ __launch_bounds__(256)
void build_rw_kernel(const float* __restrict__ weight,
                     const float* __restrict__ rm,
                     ushort_t* __restrict__ rw) {
    __shared__ float rms[N_ * 81];        // 324 floats
    int tid = threadIdx.x;
    int b = blockIdx.y;
    for (int j = tid; j < N_ * 81; j += 256)   // 324 > 256: MUST loop (R2 bug)
        rms[j] = rm[b * N_ * 81 + j];
    __syncthreads();

    int idx = blockIdx.x * 256 + tid;     // cout*256 + cin
    int cout = idx >> 8, cin = idx & 255;

    float wv[N_][9];
#pragma unroll
    for (int n = 0; n < N_; ++n)
#pragma unroll
        for (int q = 0; q < 9; ++q)
            wv[n][q] = weight[(size_t)(n * (COUT * CIN) + idx) * 9 + q];

    ushort_t* dst = rw + (size_t)(b * COUT + cout) * K_TOT + cin;
#pragma unroll
    for (int p = 0; p < 9; ++p) {
        float s = 0.f;
#pragma unroll
        for (int n = 0; n < N_; ++n)
#pragma unroll
            for (int q = 0; q < 9; ++q)
                s += rms[n * 81 + p * 9 + q] * wv[n][q];
        dst[p * 256] = f2bf(s);           // coalesced across cin lanes
    }
}

// ---------------------------------------------------------------------------
// Kernel 2b: cast x (fp32) -> xh (bf16), vectorized
// ---------------------------------------------------------------------------
__global__ __launch_bounds__(256)
void cast_x_kernel(const float* __restrict__ x, ushort_t* __restrict__ xh) {
    int i = blockIdx.x * 256 + threadIdx.x;           // one float4 per thread
    const float4 v = ((const float4*)x)[i];
    ushort_t o[4] = { f2bf(v.x), f2bf(v.y), f2bf(v.z), f2bf(v.w) };
    ((ulong1*)xh)[i] = *(ulong1*)o;                   // 8B store
}

// ---------------------------------------------------------------------------
// Kernel 3: implicit-GEMM conv, p-major K. Block tile: 128 cout x 128 px
// (2 image rows). 256 thr = 4 waves (2x2), each wave 64x64 -> acc[4][4].
// Per k-tile (BK=32): fixed tap p -> uniform (ph,pw), cin range of 32.
// ---------------------------------------------------------------------------
__global__ __launch_bounds__(256)
void conv_kernel(const ushort_t* __restrict__ xh,
                 const ushort_t* __restrict__ rw,
                 float* __restrict__ out) {
    int bid = blockIdx.x;
    int mt = bid & 1;            // cout tile (2)
    int rp = (bid >> 1) & 31;    // row pair
    int b  = bid >> 6;           // sample
    int m0 = mt * 128;
    int y0 = rp * 2;
    int tid = threadIdx.x;

    __shared__ __align__(16) ushort_t As[128][40];   // 128 couts x 32 k (+pad)
    __shared__ __align__(16) ushort_t Bs[128][40];   // 128 px    x 32 k (+pad)

    int lane = tid & 63;
    int wid  = tid >> 6;
    int wr = wid >> 1, wc = wid & 1;

    f32x4 acc[4][4] = {};

    const ushort_t* rwb = rw + (size_t)(b * COUT + m0) * K_TOT;
    const ushort_t* xb  = xh + (size_t)b * CIN * HW;

    // A staging: 512 16B-chunks (128 rows x 4), 2 per thread
    int ar0 = tid >> 1, aseg0 = (tid & 1) * 2;       // rows tid>>1, segs {0,1} or {2,3}
    // B staging: thread owns px = tid&127, k-half sub = tid>>7 (16 k each)
    int bpx  = tid & 127;
    int bsub = tid >> 7;
    int prow = bpx >> 6;         // which of the 2 image rows
    int xcol = bpx & 63;

    for (int kt = 0; kt < K_TOT / 32; ++kt) {
        int k0 = kt * 32;
        int p  = k0 >> 8;        // uniform tap index
        int cin0 = k0 & 255;
        int ph = p / 3, pw = p - 3 * ph;

        // ---- stage A tile (rw contiguous in k) ----
        {
            const int4 v0 = *(const int4*)(rwb + (size_t)ar0 * K_TOT + k0 + aseg0 * 8);
            const int4 v1 = *(const int4*)(rwb + (size_t)ar0 * K_TOT + k0 + aseg0 * 8 + 8);
            *(int4*)(&As[ar0][aseg0 * 8]) = v0;
            *(int4*)(&As[ar0][aseg0 * 8 + 8]) = v1;
        }
        // ---- stage B tile: 16 coalesced u16 loads, 2x ds_write_b128 ----
        {
            int yy = y0 + prow + ph - 1;
            int xx = xcol + pw - 1;
            bool ok = ((unsigned)yy < (unsigned)H_) && ((unsigned)xx < (unsigned)W_);
            const ushort_t* gp = xb + ((size_t)(cin0 + bsub * 16) * H_ + (yy & 63)) * W_ + (xx & 63);
            short8 v0 = {}, v1 = {};
            if (ok) {
#pragma unroll
                for (int j = 0; j < 8; ++j) v0[j] = (short)gp[(size_t)j * HW];
#pragma unroll
                for (int j = 0; j < 8; ++j) v1[j] = (short)gp[(size_t)(j + 8) * HW];
            }
            *(short8*)(&Bs[bpx][bsub * 16])     = v0;
            *(short8*)(&Bs[bpx][bsub * 16 + 8]) = v1;
        }
        __syncthreads();

        // ---- fragments + MFMA: 16 per wave ----
        int kb = (lane >> 4) * 8;
        int rA = lane & 15;
        short8 af[4], bf[4];
#pragma unroll
        for (int mi = 0; mi < 4; ++mi)
            af[mi] = *(const short8*)(&As[wr * 64 + mi * 16 + rA][kb]);
#pragma unroll
        for (int ni = 0; ni < 4; ++ni)
            bf[ni] = *(const short8*)(&Bs[wc * 64 + ni * 16 + rA][kb]);
#pragma unroll
        for (int mi = 0; mi < 4; ++mi)
#pragma unroll
            for (int ni = 0; ni < 4; ++ni)
                acc[mi][ni] = __builtin_amdgcn_mfma_f32_16x16x32_bf16(af[mi], bf[ni], acc[mi][ni], 0, 0, 0);
        __syncthreads();
    }

    // ---- epilogue: D[row=(lane>>4)*4+r][col=lane&15] ----
    int row0 = (lane >> 4) * 4;
    int col  = lane & 15;
    float* outb = out + (size_t)(b * COUT + m0) * HW + (size_t)y0 * W_;
#pragma unroll
    for (int mi = 0; mi < 4; ++mi)
#pragma unroll
        for (int ni = 0; ni < 4; ++ni)
#pragma unroll
            for (int r = 0; r < 4; ++r) {
                int m = wr * 64 + mi * 16 + row0 + r;
                int n = wc * 64 + ni * 16 + col;      // px within the 128-px tile
                outb[(size_t)m * HW + n] = acc[mi][ni][r];
            }
}

// ---------------------------------------------------------------------------
extern "C" void kernel_launch(void* const* d_in, const int* in_sizes, int n_in,
                              void* d_out, int out_size, void* d_ws, size_t ws_size,
                              hipStream_t stream) {
    const float* x      = (const float*)d_in[0];
    const float* alphas = (const float*)d_in[1];
    const float* angles = (const float*)d_in[2];
    const float* weight = (const float*)d_in[3];
    float* out = (float*)d_out;

    // workspace layout
    ushort_t* rw = (ushort_t*)d_ws;                                   // 18.9 MB
    ushort_t* xh = (ushort_t*)((char*)d_ws + (size_t)B_ * COUT * K_TOT * 2); // 33.6 MB
    float*    rm = (float*)((char*)d_ws + (size_t)B_ * COUT * K_TOT * 2
                                        + (size_t)B_ * CIN * HW * 2); // 20.7 KB

    rot_mats_kernel<<<1, 64, 0, stream>>>(alphas, angles, rm);
    build_rw_kernel<<<dim3(COUT * CIN / 256, B_), 256, 0, stream>>>(weight, rm, rw);
    cast_x_kernel<<<(B_ * CIN * HW / 4) / 256, 256, 0, stream>>>(x, xh);
    conv_kernel<<<B_ * 32 * 2, 256, 0, stream>>>(xh, rw, out);
}

// Round 5
// 160.938 us; speedup vs baseline: 3.9350x; 1.0127x over previous
//
#include <hip/hip_runtime.h>
#include <hip/hip_bf16.h>

#define B_    16
#define N_    4
#define COUT  256
#define CIN   256
#define H_    64
#define W_    64
#define K_TOT (CIN * 9)   // 2304, k = p*256 + cin  (p-major)
#define HW    (H_ * W_)   // 4096
#define NT    (K_TOT / 32) // 72 k-tiles

typedef __attribute__((ext_vector_type(8))) short short8;
typedef __attribute__((ext_vector_type(4))) float f32x4;
typedef unsigned short ushort_t;

static __device__ __forceinline__ ushort_t f2bf(float f) {
    __hip_bfloat16 h = __float2bfloat16(f);
    return *reinterpret_cast<ushort_t*>(&h);
}

// ---------------------------------------------------------------------------
// Kernel 1: 9x9 rotation matrices, scaled by alpha.  rm[b*N_+n][9][9] floats.
// ---------------------------------------------------------------------------
__global__ void rot_mats_kernel(const float* __restrict__ alphas,
                                const float* __restrict__ angles,
                                float* __restrict__ rm) {
    int i = threadIdx.x;
    if (i >= B_ * N_) return;
    float th = angles[i], al = alphas[i];
    float xc = cosf(th), ys = sinf(th);
    float a = xc - ys, b = xc * ys, c = xc + ys;
    float r[81];
#pragma unroll
    for (int j = 0; j < 81; ++j) r[j] = 0.f;
    if (th >= 0.f) {
        r[0] = a;          r[1] = 1.f - a;
        r[10] = xc - b;    r[11] = b;        r[13] = 1.f - c + b; r[14] = ys - b;
        r[20] = a;         r[23] = 1.f - a;
        r[27] = b;         r[28] = ys - b;   r[30] = xc - b;      r[31] = 1.f - c + b;
        r[40] = 1.f;
        r[49] = 1.f - c + b; r[50] = xc - b; r[52] = ys - b;      r[53] = b;
        r[57] = 1.f - a;   r[60] = a;
        r[66] = ys - b;    r[67] = 1.f - c + b; r[69] = b;        r[70] = xc - b;
        r[79] = 1.f - a;   r[80] = a;
    } else {
        r[0] = c;          r[3] = 1.f - c;
        r[9] = -b;         r[10] = xc + b;   r[12] = b - ys;      r[13] = 1.f - a - b;
        r[19] = 1.f - c;   r[20] = c;
        r[30] = xc + b;    r[31] = 1.f - a - b; r[33] = -b;       r[34] = b - ys;
        r[40] = 1.f;
        r[46] = b - ys;    r[47] = -b;       r[49] = 1.f - a - b; r[50] = xc + b;
        r[60] = c;         r[61] = 1.f - c;
        r[67] = 1.f - a - b; r[68] = b - ys; r[70] = xc + b;      r[71] = -b;
        r[77] = 1.f - c;   r[80] = c;
    }
#pragma unroll
    for (int j = 0; j < 81; ++j) rm[i * 81 + j] = r[j] * al;
}

// ---------------------------------------------------------------------------
// Kernel 2: rw[b][cout][p*256 + cin] (bf16, p-major K layout)
// ---------------------------------------------------------------------------
__global__ __launch_bounds__(256)
void build_rw_kernel(const float* __restrict__ weight,
                     const float* __restrict__ rm,
                     ushort_t* __restrict__ rw) {
    __shared__ float rms[N_ * 81];        // 324 floats
    int tid = threadIdx.x;
    int b = blockIdx.y;
    for (int j = tid; j < N_ * 81; j += 256)
        rms[j] = rm[b * N_ * 81 + j];
    __syncthreads();

    int idx = blockIdx.x * 256 + tid;     // cout*256 + cin
    int cout = idx >> 8, cin = idx & 255;

    float wv[N_][9];
#pragma unroll
    for (int n = 0; n < N_; ++n)
#pragma unroll
        for (int q = 0; q < 9; ++q)
            wv[n][q] = weight[(size_t)(n * (COUT * CIN) + idx) * 9 + q];

    ushort_t* dst = rw + (size_t)(b * COUT + cout) * K_TOT + cin;
#pragma unroll
    for (int p = 0; p < 9; ++p) {
        float s = 0.f;
#pragma unroll
        for (int n = 0; n < N_; ++n)
#pragma unroll
            for (int q = 0; q < 9; ++q)
                s += rms[n * 81 + p * 9 + q] * wv[n][q];
        dst[p * 256] = f2bf(s);
    }
}

// ---------------------------------------------------------------------------
// Kernel 2b: cast x (fp32) -> xh (bf16), vectorized
// ---------------------------------------------------------------------------
__global__ __launch_bounds__(256)
void cast_x_kernel(const float* __restrict__ x, ushort_t* __restrict__ xh) {
    int i = blockIdx.x * 256 + threadIdx.x;
    const float4 v = ((const float4*)x)[i];
    ushort_t o[4] = { f2bf(v.x), f2bf(v.y), f2bf(v.z), f2bf(v.w) };
    ((ulong1*)xh)[i] = *(ulong1*)o;
}

// ---------------------------------------------------------------------------
// Kernel 3: implicit-GEMM conv. 128 cout x 128 px tile, dbuf LDS,
// single barrier per k-tile, reg-staged prefetch (T14).
// LDS slot swizzle: seg' = (seg + (row>>1)) & 3  (covers all 8 16B slots/wave).
// XCD swizzle: 1024 blocks = 8 x 128 (bijective; 2 samples per XCD).
// ---------------------------------------------------------------------------
__global__ __launch_bounds__(256)
void conv_kernel(const ushort_t* __restrict__ xh,
                 const ushort_t* __restrict__ rw,
                 float* __restrict__ out) {
    int bid0 = blockIdx.x;
    int bid = (bid0 & 7) * 128 + (bid0 >> 3);   // grid=1024: bijective
    int mt = bid & 1;            // cout tile (2)
    int rp = (bid >> 1) & 31;    // row pair
    int b  = bid >> 6;           // sample
    int m0 = mt * 128;
    int y0 = rp * 2;
    int tid = threadIdx.x;

    // rows of 32 u16 (64B); slot swizzle (seg + (row>>1)) & 3
    __shared__ __align__(16) ushort_t As[2][128][32];   // 2 x 8 KB
    __shared__ __align__(16) ushort_t Bs[2][128][32];   // 2 x 8 KB

    int lane = tid & 63;
    int wid  = tid >> 6;
    int wr = wid >> 1, wc = wid & 1;

    f32x4 acc[4][4] = {};

    const ushort_t* rwb = rw + (size_t)(b * COUT + m0) * K_TOT;
    const ushort_t* xb  = xh + (size_t)b * CIN * HW;

    // A staging: thread -> row tid>>1, segs {0,1} or {2,3}
    int ar0 = tid >> 1, aseg0 = (tid & 1) * 2;
    // B staging: thread -> px tid&127, k-half tid>>7 (16 k each)
    int bpx  = tid & 127;
    int bsub = tid >> 7;
    int prow = bpx >> 6;
    int xcol = bpx & 63;

    int4 pa0, pa1; short8 pv0, pv1;

#define SWZ(seg, row) ((((seg) + ((row) >> 1)) & 3) * 8)

#define LOAD_TILE(KT)                                                          \
    {                                                                          \
        int k0 = (KT) * 32;                                                    \
        pa0 = *(const int4*)(rwb + (size_t)ar0 * K_TOT + k0 + aseg0 * 8);      \
        pa1 = *(const int4*)(rwb + (size_t)ar0 * K_TOT + k0 + aseg0 * 8 + 8);  \
        int p = k0 >> 8; int cin0 = k0 & 255;                                  \
        int ph = p / 3, pw = p - 3 * ph;                                       \
        int yy = y0 + prow + ph - 1, xx = xcol + pw - 1;                       \
        bool ok = ((unsigned)yy < (unsigned)H_) && ((unsigned)xx < (unsigned)W_); \
        const ushort_t* gp = xb + ((size_t)(cin0 + bsub * 16) * H_ + (yy & 63)) * W_ + (xx & 63); \
        pv0 = short8{}; pv1 = short8{};                                        \
        if (ok) {                                                              \
            _Pragma("unroll")                                                  \
            for (int j = 0; j < 8; ++j) pv0[j] = (short)gp[(size_t)j * HW];    \
            _Pragma("unroll")                                                  \
            for (int j = 0; j < 8; ++j) pv1[j] = (short)gp[(size_t)(j + 8) * HW]; \
        }                                                                      \
    }

#define WRITE_TILE(BUF)                                                        \
    {                                                                          \
        *(int4*)(&As[BUF][ar0][SWZ(aseg0, ar0)]) = pa0;                        \
        *(int4*)(&As[BUF][ar0][SWZ(aseg0 + 1, ar0)]) = pa1;                    \
        *(short8*)(&Bs[BUF][bpx][SWZ(2 * bsub, bpx)]) = pv0;                   \
        *(short8*)(&Bs[BUF][bpx][SWZ(2 * bsub + 1, bpx)]) = pv1;               \
    }

    LOAD_TILE(0);
    WRITE_TILE(0);
    __syncthreads();

    int kseg = lane >> 4;      // fragment k-seg 0..3
    int rA   = lane & 15;
    int cur = 0;

    for (int kt = 0; kt < NT; ++kt) {
        if (kt + 1 < NT) LOAD_TILE(kt + 1);

        short8 af[4], bf[4];
#pragma unroll
        for (int mi = 0; mi < 4; ++mi) {
            int row = wr * 64 + mi * 16 + rA;
            af[mi] = *(const short8*)(&As[cur][row][SWZ(kseg, row)]);
        }
#pragma unroll
        for (int ni = 0; ni < 4; ++ni) {
            int row = wc * 64 + ni * 16 + rA;
            bf[ni] = *(const short8*)(&Bs[cur][row][SWZ(kseg, row)]);
        }
#pragma unroll
        for (int mi = 0; mi < 4; ++mi)
#pragma unroll
            for (int ni = 0; ni < 4; ++ni)
                acc[mi][ni] = __builtin_amdgcn_mfma_f32_16x16x32_bf16(af[mi], bf[ni], acc[mi][ni], 0, 0, 0);

        if (kt + 1 < NT) {
            WRITE_TILE(cur ^ 1);
            __syncthreads();
        }
        cur ^= 1;
    }
#undef LOAD_TILE
#undef WRITE_TILE
#undef SWZ

    // ---- epilogue: D[row=(lane>>4)*4+r][col=lane&15] ----
    int row0 = (lane >> 4) * 4;
    int col  = lane & 15;
    float* outb = out + (size_t)(b * COUT + m0) * HW + (size_t)y0 * W_;
#pragma unroll
    for (int mi = 0; mi < 4; ++mi)
#pragma unroll
        for (int ni = 0; ni < 4; ++ni)
#pragma unroll
            for (int r = 0; r < 4; ++r) {
                int m = wr * 64 + mi * 16 + row0 + r;
                int n = wc * 64 + ni * 16 + col;
                outb[(size_t)m * HW + n] = acc[mi][ni][r];
            }
}

// ---------------------------------------------------------------------------
extern "C" void kernel_launch(void* const* d_in, const int* in_sizes, int n_in,
                              void* d_out, int out_size, void* d_ws, size_t ws_size,
                              hipStream_t stream) {
    const float* x      = (const float*)d_in[0];
    const float* alphas = (const float*)d_in[1];
    const float* angles = (const float*)d_in[2];
    const float* weight = (const float*)d_in[3];
    float* out = (float*)d_out;

    ushort_t* rw = (ushort_t*)d_ws;                                          // 18.9 MB
    ushort_t* xh = (ushort_t*)((char*)d_ws + (size_t)B_ * COUT * K_TOT * 2); // 33.6 MB
    float*    rm = (float*)((char*)d_ws + (size_t)B_ * COUT * K_TOT * 2
                                        + (size_t)B_ * CIN * HW * 2);        // 20.7 KB

    rot_mats_kernel<<<1, 64, 0, stream>>>(alphas, angles, rm);
    build_rw_kernel<<<dim3(COUT * CIN / 256, B_), 256, 0, stream>>>(weight, rm, rw);
    cast_x_kernel<<<(B_ * CIN * HW / 4) / 256, 256, 0, stream>>>(x, xh);
    conv_kernel<<<B_ * 32 * 2, 256, 0, stream>>>(xh, rw, out);
}